// Round 3
// baseline (354.042 us; speedup 1.0000x reference)
//
#include <hip/hip_runtime.h>

// out[s,n, l*4096 + i*64 + j] = norm_l(i,j) * sum_m c_l[s,n,m,i]*c_l[s,n,m,j]
// norm_l = (2l+1)^-1/2 off-diagonal, additionally * 3^-1/2 on diagonal.
// S*N = 24000 pairs, Q=64, output 24000*16384 fp32 = 1.57 GB -> write-BW bound.
// R3: nontemporal via clang ext_vector_type (HIP_vector_type rejected by builtin).

#define NTHREADS 256

typedef __attribute__((ext_vector_type(4))) float f32x4;

__global__ __launch_bounds__(NTHREADS) void ps_kernel(
    const float* __restrict__ c0, const float* __restrict__ c1,
    const float* __restrict__ c2, const float* __restrict__ c3,
    float* __restrict__ out, int total)
{
    __shared__ float lds[16 * 64];  // 16 m-rows (l0:0, l1:1..3, l2:4..8, l3:9..15) x 64 q

    const int blk = blockIdx.x;
    if (blk >= total) return;
    const int t = threadIdx.x;

    // ---- stage c into LDS: one f32x4 per thread (256 x4 = 1024 floats) ----
    {
        const float* src;
        int local;       // float4 index within region
        int ldsbase;     // float index of region start in lds
        if (t < 16)       { src = c0 + (size_t)blk * (1 * 64); local = t;       ldsbase = 0;   }
        else if (t < 64)  { src = c1 + (size_t)blk * (3 * 64); local = t - 16;  ldsbase = 64;  }
        else if (t < 144) { src = c2 + (size_t)blk * (5 * 64); local = t - 64;  ldsbase = 256; }
        else              { src = c3 + (size_t)blk * (7 * 64); local = t - 144; ldsbase = 576; }
        f32x4 v = __builtin_nontemporal_load(reinterpret_cast<const f32x4*>(src) + local);
        *reinterpret_cast<f32x4*>(&lds[ldsbase + local * 4]) = v;
    }
    __syncthreads();

    const int jq = t & 15;        // j-quad: columns 4*jq .. 4*jq+3
    const int i0 = t >> 4;        // base row 0..15; rows i0 + 16*r, r=0..3
    const int jbase = jq * 4;

    const float INV_SQRT3 = 0.57735026918962576f;
    // cg = (2l+1)^-1/2, exact fp32 constants
    const float CG[4] = {1.0f, 0.57735026918962576f, 0.44721359549995794f, 0.37796447300922720f};
    const int MOFF[4] = {0, 1, 4, 9};

    f32x4* outv = reinterpret_cast<f32x4*>(out);
    const size_t obase4 = (size_t)blk * (16384 / 4);  // f32x4 index of this pair's output

    #pragma unroll
    for (int l = 0; l < 4; ++l) {
        const int nm = 2 * l + 1;
        const int moff = MOFF[l];
        const float cg = CG[l];

        // per-thread column fragment: cj[m] = c[m][4jq..4jq+3]
        f32x4 cj[7];
        #pragma unroll
        for (int m = 0; m < nm; ++m)
            cj[m] = *reinterpret_cast<const f32x4*>(&lds[(moff + m) * 64 + jbase]);

        #pragma unroll
        for (int r = 0; r < 4; ++r) {
            const int i = i0 + r * 16;
            float ax = 0.f, ay = 0.f, az = 0.f, aw = 0.f;
            #pragma unroll
            for (int m = 0; m < nm; ++m) {
                const float ci = lds[(moff + m) * 64 + i];  // broadcast within 16-lane group
                ax += ci * cj[m].x;
                ay += ci * cj[m].y;
                az += ci * cj[m].z;
                aw += ci * cj[m].w;
            }
            // norm: cg everywhere, extra 1/sqrt(3) on the diagonal element (static per component)
            ax *= cg * ((i == jbase + 0) ? INV_SQRT3 : 1.0f);
            ay *= cg * ((i == jbase + 1) ? INV_SQRT3 : 1.0f);
            az *= cg * ((i == jbase + 2) ? INV_SQRT3 : 1.0f);
            aw *= cg * ((i == jbase + 3) ? INV_SQRT3 : 1.0f);

            f32x4 v; v.x = ax; v.y = ay; v.z = az; v.w = aw;
            __builtin_nontemporal_store(v, &outv[obase4 + (size_t)l * 1024 + (size_t)i * 16 + jq]);
        }
    }
}

extern "C" void kernel_launch(void* const* d_in, const int* in_sizes, int n_in,
                              void* d_out, int out_size, void* d_ws, size_t ws_size,
                              hipStream_t stream) {
    const float* c0 = (const float*)d_in[0];
    const float* c1 = (const float*)d_in[1];
    const float* c2 = (const float*)d_in[2];
    const float* c3 = (const float*)d_in[3];
    float* out = (float*)d_out;

    const int total = in_sizes[0] / 64;  // S*N pairs (c0 is (S,N,1,64))

    ps_kernel<<<dim3(total), dim3(NTHREADS), 0, stream>>>(c0, c1, c2, c3, out, total);
}

// Round 4
// 338.102 us; speedup vs baseline: 1.0471x; 1.0471x over previous
//
#include <hip/hip_runtime.h>

// out[s,n, l*4096 + i*64 + j] = norm_l(i,j) * sum_m c_l[s,n,m,i]*c_l[s,n,m,j]
// norm_l = (2l+1)^-1/2 off-diagonal, additionally * 3^-1/2 on diagonal.
// S*N = 24000 pairs, Q=64, output 1.57 GB fp32 -> write-BW bound.
// R4: revert nontemporal (hurt: 328->354). Persistent blocks, PPB pairs per
//     block, double-buffered LDS with issue-early prefetch (T14) so the
//     global-load latency + barrier drain hides under the previous pair's
//     compute+store phase.

#define NTHREADS 256
#define PPB 12

typedef __attribute__((ext_vector_type(4))) float f32x4;

__global__ __launch_bounds__(NTHREADS) void ps_kernel(
    const float* __restrict__ c0, const float* __restrict__ c1,
    const float* __restrict__ c2, const float* __restrict__ c3,
    float* __restrict__ out, int total)
{
    __shared__ float lds[2][16 * 64];  // double-buffered: 16 m-rows x 64 q

    const int t = threadIdx.x;

    // ---- per-thread staging role (fixed across pairs) ----
    const float* src;     // base of source array
    int local;            // f32x4 index within this pair's region
    int ldsoff;           // float offset of region start in lds
    int stride;           // floats per pair in source array
    if (t < 16)       { src = c0; local = t;       ldsoff = 0;   stride = 1 * 64; }
    else if (t < 64)  { src = c1; local = t - 16;  ldsoff = 64;  stride = 3 * 64; }
    else if (t < 144) { src = c2; local = t - 64;  ldsoff = 256; stride = 5 * 64; }
    else              { src = c3; local = t - 144; ldsoff = 576; stride = 7 * 64; }

    const int pstart = blockIdx.x * PPB;
    const int pend   = (pstart + PPB < total) ? (pstart + PPB) : total;
    if (pstart >= total) return;

    const int jq = t & 15;        // j-quad: columns 4*jq .. 4*jq+3
    const int i0 = t >> 4;        // base row 0..15; rows i0 + 16*r, r=0..3
    const int jbase = jq * 4;

    const float INV_SQRT3 = 0.57735026918962576f;
    const float CG[4] = {1.0f, 0.57735026918962576f, 0.44721359549995794f, 0.37796447300922720f};
    const int MOFF[4] = {0, 1, 4, 9};

    f32x4* outv = reinterpret_cast<f32x4*>(out);

    // prologue: load pair pstart
    f32x4 v = *(reinterpret_cast<const f32x4*>(src + (size_t)pstart * stride) + local);

    int cur = 0;
    for (int p = pstart; p < pend; ++p) {
        // write staged pair into current LDS buffer
        *reinterpret_cast<f32x4*>(&lds[cur][ldsoff + local * 4]) = v;
        __syncthreads();

        // issue next pair's load early — hides HBM latency under compute
        if (p + 1 < pend)
            v = *(reinterpret_cast<const f32x4*>(src + (size_t)(p + 1) * stride) + local);

        const float* L = lds[cur];
        const size_t obase4 = (size_t)p * (16384 / 4);

        #pragma unroll
        for (int l = 0; l < 4; ++l) {
            const int nm = 2 * l + 1;
            const int moff = MOFF[l];
            const float cg = CG[l];

            f32x4 cj[7];
            #pragma unroll
            for (int m = 0; m < nm; ++m)
                cj[m] = *reinterpret_cast<const f32x4*>(&L[(moff + m) * 64 + jbase]);

            #pragma unroll
            for (int r = 0; r < 4; ++r) {
                const int i = i0 + r * 16;
                float ax = 0.f, ay = 0.f, az = 0.f, aw = 0.f;
                #pragma unroll
                for (int m = 0; m < nm; ++m) {
                    const float ci = L[(moff + m) * 64 + i];  // broadcast in 16-lane group
                    ax += ci * cj[m].x;
                    ay += ci * cj[m].y;
                    az += ci * cj[m].z;
                    aw += ci * cj[m].w;
                }
                ax *= cg * ((i == jbase + 0) ? INV_SQRT3 : 1.0f);
                ay *= cg * ((i == jbase + 1) ? INV_SQRT3 : 1.0f);
                az *= cg * ((i == jbase + 2) ? INV_SQRT3 : 1.0f);
                aw *= cg * ((i == jbase + 3) ? INV_SQRT3 : 1.0f);

                f32x4 o; o.x = ax; o.y = ay; o.z = az; o.w = aw;
                outv[obase4 + (size_t)l * 1024 + (size_t)i * 16 + jq] = o;
            }
        }

        cur ^= 1;
        __syncthreads();  // buffer cur reused 2 iters later; one barrier/iter suffices
    }
}

extern "C" void kernel_launch(void* const* d_in, const int* in_sizes, int n_in,
                              void* d_out, int out_size, void* d_ws, size_t ws_size,
                              hipStream_t stream) {
    const float* c0 = (const float*)d_in[0];
    const float* c1 = (const float*)d_in[1];
    const float* c2 = (const float*)d_in[2];
    const float* c3 = (const float*)d_in[3];
    float* out = (float*)d_out;

    const int total = in_sizes[0] / 64;  // S*N pairs (c0 is (S,N,1,64))
    const int grid = (total + PPB - 1) / PPB;

    ps_kernel<<<dim3(grid), dim3(NTHREADS), 0, stream>>>(c0, c1, c2, c3, out, total);
}

// Round 5
// 329.412 us; speedup vs baseline: 1.0748x; 1.0264x over previous
//
#include <hip/hip_runtime.h>

// out[s,n, l*4096 + i*64 + j] = norm_l(i,j) * sum_m c_l[s,n,m,i]*c_l[s,n,m,j]
// norm_l = (2l+1)^-1/2 off-diagonal, additionally * 3^-1/2 on diagonal.
// S*N = 24000 pairs, Q=64, output 1.57 GB fp32 -> write-BW bound, but R1-R4
// showed we are VALU-issue-bound at the margin. R5: packed fp32 math —
// f32x4 accumulators (v_pk_fma_f32), cg folded into cj at load, diagonal fix
// as 4 precomputed per-thread vectors. ~2x fewer VALU instructions.

#define NTHREADS 256

typedef __attribute__((ext_vector_type(4))) float f32x4;

__global__ __launch_bounds__(NTHREADS) void ps_kernel(
    const float* __restrict__ c0, const float* __restrict__ c1,
    const float* __restrict__ c2, const float* __restrict__ c3,
    float* __restrict__ out, int total)
{
    __shared__ float lds[16 * 64];  // 16 m-rows (l0:0, l1:1..3, l2:4..8, l3:9..15) x 64 q

    const int blk = blockIdx.x;
    const int t = threadIdx.x;

    // ---- stage c into LDS: one f32x4 per thread (256 x4 = 1024 floats) ----
    {
        const float* src;
        int local;       // f32x4 index within region
        int ldsbase;     // float index of region start in lds
        if (t < 16)       { src = c0 + (size_t)blk * (1 * 64); local = t;       ldsbase = 0;   }
        else if (t < 64)  { src = c1 + (size_t)blk * (3 * 64); local = t - 16;  ldsbase = 64;  }
        else if (t < 144) { src = c2 + (size_t)blk * (5 * 64); local = t - 64;  ldsbase = 256; }
        else              { src = c3 + (size_t)blk * (7 * 64); local = t - 144; ldsbase = 576; }
        f32x4 v = *(reinterpret_cast<const f32x4*>(src) + local);
        *reinterpret_cast<f32x4*>(&lds[ldsbase + local * 4]) = v;
    }
    __syncthreads();

    const int jq = t & 15;        // j-quad: columns 4*jq .. 4*jq+3
    const int i0 = t >> 4;        // base row 0..15; rows i0 + 16*r, r=0..3
    const int jbase = jq * 4;

    const float INV_SQRT3 = 0.57735026918962576f;
    const float CG[4] = {1.0f, 0.57735026918962576f, 0.44721359549995794f, 0.37796447300922720f};
    const int MOFF[4] = {0, 1, 4, 9};

    // per-thread diagonal fix, independent of l: row i = i0+16r hits the
    // diagonal at component cc iff i == jbase+cc.
    f32x4 dfix[4];
    #pragma unroll
    for (int r = 0; r < 4; ++r) {
        const int i = i0 + 16 * r;
        f32x4 d;
        d.x = (i == jbase + 0) ? INV_SQRT3 : 1.0f;
        d.y = (i == jbase + 1) ? INV_SQRT3 : 1.0f;
        d.z = (i == jbase + 2) ? INV_SQRT3 : 1.0f;
        d.w = (i == jbase + 3) ? INV_SQRT3 : 1.0f;
        dfix[r] = d;
    }

    f32x4* outv = reinterpret_cast<f32x4*>(out);
    const size_t obase4 = (size_t)blk * (16384 / 4);

    #pragma unroll
    for (int l = 0; l < 4; ++l) {
        const int nm = 2 * l + 1;
        const int moff = MOFF[l];
        const float cg = CG[l];

        // column fragment, pre-scaled by cg (vector mul -> v_pk_mul_f32)
        f32x4 cj[7];
        #pragma unroll
        for (int m = 0; m < nm; ++m)
            cj[m] = (*reinterpret_cast<const f32x4*>(&lds[(moff + m) * 64 + jbase])) * cg;

        #pragma unroll
        for (int r = 0; r < 4; ++r) {
            const int i = i0 + r * 16;
            f32x4 acc = {0.0f, 0.0f, 0.0f, 0.0f};
            #pragma unroll
            for (int m = 0; m < nm; ++m) {
                const float ci = lds[(moff + m) * 64 + i];  // broadcast in 16-lane group
                acc += ci * cj[m];                          // v_pk_fma_f32 x2
            }
            acc *= dfix[r];                                 // v_pk_mul_f32 x2
            outv[obase4 + (size_t)l * 1024 + (size_t)i * 16 + jq] = acc;
        }
    }
}

extern "C" void kernel_launch(void* const* d_in, const int* in_sizes, int n_in,
                              void* d_out, int out_size, void* d_ws, size_t ws_size,
                              hipStream_t stream) {
    const float* c0 = (const float*)d_in[0];
    const float* c1 = (const float*)d_in[1];
    const float* c2 = (const float*)d_in[2];
    const float* c3 = (const float*)d_in[3];
    float* out = (float*)d_out;

    const int total = in_sizes[0] / 64;  // S*N pairs (c0 is (S,N,1,64))

    ps_kernel<<<dim3(total), dim3(NTHREADS), 0, stream>>>(c0, c1, c2, c3, out, total);
}